// Round 3
// baseline (11203.018 us; speedup 1.0000x reference)
//
#include <hip/hip_runtime.h>
#include <math.h>

#define B_ROWS 8192
#define P_KEYS 2048
#define D_DIM  768
#define L_LEN  5
#define K_SEL  5
#define EPSV   1e-8f

#define ROW_TILE 128
#define COL_TILE 128
#define KB 16
#define NCB (P_KEYS / COL_TILE)   // 16 column blocks

// sorted ascending (v[0] best). Tie-break: lower index wins (jax top_k semantics).
__device__ inline void insert5(float (&v)[K_SEL], int (&ix)[K_SEL], float nv, int ni) {
    if (nv < v[K_SEL-1] || (nv == v[K_SEL-1] && ni < ix[K_SEL-1])) {
        v[K_SEL-1] = nv; ix[K_SEL-1] = ni;
        #pragma unroll
        for (int j = K_SEL-1; j > 0; --j) {
            bool sw = (v[j] < v[j-1]) || (v[j] == v[j-1] && ix[j] < ix[j-1]);
            if (sw) {
                float tv = v[j]; v[j] = v[j-1]; v[j-1] = tv;
                int   ti = ix[j]; ix[j] = ix[j-1]; ix[j-1] = ti;
            }
        }
    }
}

// One wave per row: inverse norms only. waves [0,B_ROWS): x -> inv_x.
// waves [B_ROWS, B_ROWS+P_KEYS): pool_key -> inv_k.
__global__ __launch_bounds__(256)
void norm_kernel(const float* __restrict__ x, const float* __restrict__ pk,
                 float* __restrict__ inv_x, float* __restrict__ inv_k) {
    int wave = (blockIdx.x * blockDim.x + threadIdx.x) >> 6;
    int lane = threadIdx.x & 63;
    bool is_x = (wave < B_ROWS);
    int row = is_x ? wave : wave - B_ROWS;
    const float* src = is_x ? (x + (size_t)row * D_DIM) : (pk + (size_t)row * D_DIM);

    const float4* s4 = (const float4*)src;
    float s = 0.f;
    #pragma unroll
    for (int i = 0; i < 3; ++i) {
        float4 v = s4[lane + 64 * i];
        s += v.x * v.x + v.y * v.y + v.z * v.z + v.w * v.w;
    }
    #pragma unroll
    for (int off = 32; off; off >>= 1) s += __shfl_xor(s, off, 64);
    float inv = 1.0f / fmaxf(sqrtf(s), EPSV);
    if (lane == 0) {
        if (is_x) inv_x[row] = inv; else inv_k[row] = inv;
    }
}

// Fused fp32 GEMM (dist = 1 - x_hat . k_hat) + per-row top-5 per 128-col block.
// grid = (NCB, B_ROWS/ROW_TILE). block 256 = 16x16, each thread 8x8 outputs
// arranged as 2x2 blocks of 4x4 (rows ty*4+{0..3}/+64, cols tx*4+{0..3}/+64).
__global__ __launch_bounds__(256, 4)
void gemm_top5_kernel(const float* __restrict__ x, const float* __restrict__ pk,
                      const float* __restrict__ inv_x, const float* __restrict__ inv_k,
                      float* __restrict__ cand_val, int* __restrict__ cand_idx) {
    const int cb   = blockIdx.x;
    const int rb   = blockIdx.y;
    const int row0 = rb * ROW_TILE;
    const int col0 = cb * COL_TILE;

    __shared__ float As[KB][ROW_TILE + 4];   // k-major; stride 132 floats (16B-aligned rows)
    __shared__ float Bs[KB][COL_TILE + 4];

    const int tid = threadIdx.x;
    const int tx = tid & 15, ty = tid >> 4;

    // staging: thread loads rows sr & sr+64, k-cols sk..sk+3 of both panels
    const int sr = tid >> 2;          // 0..63
    const int sk = (tid & 3) * 4;     // 0,4,8,12
    const float iva0 = inv_x[row0 + sr];
    const float iva1 = inv_x[row0 + sr + 64];
    const float ivb0 = inv_k[col0 + sr];
    const float ivb1 = inv_k[col0 + sr + 64];
    const float* ap0 = x  + (size_t)(row0 + sr)      * D_DIM + sk;
    const float* ap1 = x  + (size_t)(row0 + sr + 64) * D_DIM + sk;
    const float* bp0 = pk + (size_t)(col0 + sr)      * D_DIM + sk;
    const float* bp1 = pk + (size_t)(col0 + sr + 64) * D_DIM + sk;

    float acc[8][8] = {};

    for (int k0 = 0; k0 < D_DIM; k0 += KB) {
        float4 a0 = *(const float4*)(ap0 + k0);
        float4 a1 = *(const float4*)(ap1 + k0);
        float4 b0 = *(const float4*)(bp0 + k0);
        float4 b1 = *(const float4*)(bp1 + k0);
        __syncthreads();
        As[sk+0][sr]    = a0.x * iva0; As[sk+1][sr]    = a0.y * iva0;
        As[sk+2][sr]    = a0.z * iva0; As[sk+3][sr]    = a0.w * iva0;
        As[sk+0][sr+64] = a1.x * iva1; As[sk+1][sr+64] = a1.y * iva1;
        As[sk+2][sr+64] = a1.z * iva1; As[sk+3][sr+64] = a1.w * iva1;
        Bs[sk+0][sr]    = b0.x * ivb0; Bs[sk+1][sr]    = b0.y * ivb0;
        Bs[sk+2][sr]    = b0.z * ivb0; Bs[sk+3][sr]    = b0.w * ivb0;
        Bs[sk+0][sr+64] = b1.x * ivb1; Bs[sk+1][sr+64] = b1.y * ivb1;
        Bs[sk+2][sr+64] = b1.z * ivb1; Bs[sk+3][sr+64] = b1.w * ivb1;
        __syncthreads();

        #pragma unroll
        for (int k = 0; k < KB; ++k) {
            float4 al = *(const float4*)&As[k][ty * 4];
            float4 ah = *(const float4*)&As[k][ty * 4 + 64];
            float4 bl = *(const float4*)&Bs[k][tx * 4];
            float4 bh = *(const float4*)&Bs[k][tx * 4 + 64];
            float ar[8] = {al.x, al.y, al.z, al.w, ah.x, ah.y, ah.z, ah.w};
            float br[8] = {bl.x, bl.y, bl.z, bl.w, bh.x, bh.y, bh.z, bh.w};
            #pragma unroll
            for (int i = 0; i < 8; ++i)
                #pragma unroll
                for (int j = 0; j < 8; ++j)
                    acc[i][j] += ar[i] * br[j];
        }
    }

    // epilogue: per row-slot local top5 over 8 cols, then 16-lane butterfly merge
    #pragma unroll
    for (int i = 0; i < 8; ++i) {
        float tv[K_SEL]; int tix[K_SEL];
        #pragma unroll
        for (int j = 0; j < K_SEL; ++j) { tv[j] = 3.0e38f; tix[j] = 0x7fffffff; }
        #pragma unroll
        for (int j = 0; j < 8; ++j) {
            float dv = 1.0f - acc[i][j];
            int c = col0 + tx * 4 + (j >> 2) * 64 + (j & 3);
            insert5(tv, tix, dv, c);
        }
        #pragma unroll
        for (int off = 1; off < 16; off <<= 1) {
            float ov[K_SEL]; int oi[K_SEL];
            #pragma unroll
            for (int j = 0; j < K_SEL; ++j) {
                ov[j] = __shfl_xor(tv[j], off, 16);
                oi[j] = __shfl_xor(tix[j], off, 16);
            }
            #pragma unroll
            for (int j = 0; j < K_SEL; ++j) insert5(tv, tix, ov[j], oi[j]);
        }
        if (tx == 0) {
            int grow = row0 + ty * 4 + (i >> 2) * 64 + (i & 3);
            #pragma unroll
            for (int j = 0; j < K_SEL; ++j) {
                cand_val[((size_t)grow * NCB + cb) * K_SEL + j] = tv[j];
                cand_idx[((size_t)grow * NCB + cb) * K_SEL + j] = tix[j];
            }
        }
    }
}

__global__ __launch_bounds__(256)
void merge_kernel(const float* __restrict__ cand_val, const int* __restrict__ cand_idx,
                  float* __restrict__ out_dist, int* __restrict__ final_idx) {
    int row = blockIdx.x * blockDim.x + threadIdx.x;
    if (row >= B_ROWS) return;
    float fv[K_SEL]; int fi[K_SEL];
    #pragma unroll
    for (int j = 0; j < K_SEL; ++j) { fv[j] = 3.0e38f; fi[j] = 0x7fffffff; }
    for (int t = 0; t < NCB * K_SEL; ++t)
        insert5(fv, fi, cand_val[(size_t)row * NCB * K_SEL + t],
                        cand_idx[(size_t)row * NCB * K_SEL + t]);
    #pragma unroll
    for (int j = 0; j < K_SEL; ++j) {
        out_dist[(size_t)row * K_SEL + j] = fv[j];
        final_idx[(size_t)row * K_SEL + j] = fi[j];
    }
}

// one block per (b, s): copy prompts[idx] (5*768 floats = 960 float4) to output
__global__ __launch_bounds__(256)
void gather_kernel(const float* __restrict__ prompts, const int* __restrict__ final_idx,
                   float* __restrict__ out1) {
    int bs = blockIdx.x;                 // 0 .. B_ROWS*K_SEL-1
    int p = final_idx[bs];
    const float4* src = (const float4*)(prompts + (size_t)p * (L_LEN * D_DIM));
    float4* dst = (float4*)(out1 + (size_t)bs * (L_LEN * D_DIM));
    const int n4 = (L_LEN * D_DIM) / 4;  // 960
    for (int i = threadIdx.x; i < n4; i += blockDim.x) dst[i] = src[i];
}

extern "C" void kernel_launch(void* const* d_in, const int* in_sizes, int n_in,
                              void* d_out, int out_size, void* d_ws, size_t ws_size,
                              hipStream_t stream) {
    const float* x       = (const float*)d_in[0];   // [8192, 768]
    const float* pk      = (const float*)d_in[1];   // [2048, 768]
    const float* prompts = (const float*)d_in[2];   // [2048, 5, 768]

    float* out_dist = (float*)d_out;                          // [8192, 5]
    float* out_pr   = (float*)d_out + (size_t)B_ROWS * K_SEL; // [8192, 5, 5, 768]

    char* ws = (char*)d_ws;
    float* inv_x    = (float*)(ws);                    //    32,768 B
    float* inv_k    = (float*)(ws + 32768);            //     8,192 B
    float* cand_val = (float*)(ws + 40960);            // 2,621,440 B
    int*   cand_idx = (int*)  (ws + 40960 + 2621440);  // 2,621,440 B
    int*   final_ix = (int*)  (ws + 40960 + 5242880);  //   163,840 B

    // 1) inverse norms: (B_ROWS + P_KEYS) waves, 4 waves/block
    norm_kernel<<<(B_ROWS + P_KEYS) / 4, 256, 0, stream>>>(x, pk, inv_x, inv_k);
    // 2) fused GEMM + per-colblock top5
    {
        dim3 grid(NCB, B_ROWS / ROW_TILE);
        gemm_top5_kernel<<<grid, 256, 0, stream>>>(x, pk, inv_x, inv_k, cand_val, cand_idx);
    }
    // 3) cross-colblock merge
    merge_kernel<<<B_ROWS / 256, 256, 0, stream>>>(cand_val, cand_idx, out_dist, final_ix);
    // 4) gather prompts
    gather_kernel<<<B_ROWS * K_SEL, 256, 0, stream>>>(prompts, final_ix, out_pr);
}

// Round 7
// 11149.010 us; speedup vs baseline: 1.0048x; 1.0048x over previous
//
#include <hip/hip_runtime.h>
#include <math.h>

#define B_ROWS 8192
#define P_KEYS 2048
#define D_DIM  768
#define L_LEN  5
#define K_SEL  5
#define EPSV   1e-8f

#define ROW_TILE 128
#define COL_TILE 128
#define KB 16
#define NCB (P_KEYS / COL_TILE)   // 16 column blocks

// sorted ascending (v[0] best). Tie-break: lower index wins (jax top_k semantics).
__device__ inline void insert5(float (&v)[K_SEL], int (&ix)[K_SEL], float nv, int ni) {
    if (nv < v[K_SEL-1] || (nv == v[K_SEL-1] && ni < ix[K_SEL-1])) {
        v[K_SEL-1] = nv; ix[K_SEL-1] = ni;
        #pragma unroll
        for (int j = K_SEL-1; j > 0; --j) {
            bool sw = (v[j] < v[j-1]) || (v[j] == v[j-1] && ix[j] < ix[j-1]);
            if (sw) {
                float tv = v[j]; v[j] = v[j-1]; v[j-1] = tv;
                int   ti = ix[j]; ix[j] = ix[j-1]; ix[j-1] = ti;
            }
        }
    }
}

// One wave per row: inverse norms only. waves [0,B_ROWS): x -> inv_x.
// waves [B_ROWS, B_ROWS+P_KEYS): pool_key -> inv_k.
__global__ __launch_bounds__(256)
void norm_kernel(const float* __restrict__ x, const float* __restrict__ pk,
                 float* __restrict__ inv_x, float* __restrict__ inv_k) {
    int wave = (blockIdx.x * blockDim.x + threadIdx.x) >> 6;
    int lane = threadIdx.x & 63;
    bool is_x = (wave < B_ROWS);
    int row = is_x ? wave : wave - B_ROWS;
    const float* src = is_x ? (x + (size_t)row * D_DIM) : (pk + (size_t)row * D_DIM);

    const float4* s4 = (const float4*)src;
    float s = 0.f;
    #pragma unroll
    for (int i = 0; i < 3; ++i) {
        float4 v = s4[lane + 64 * i];
        s += v.x * v.x + v.y * v.y + v.z * v.z + v.w * v.w;
    }
    #pragma unroll
    for (int off = 32; off; off >>= 1) s += __shfl_xor(s, off, 64);
    float inv = 1.0f / fmaxf(sqrtf(s), EPSV);
    if (lane == 0) {
        if (is_x) inv_x[row] = inv; else inv_k[row] = inv;
    }
}

// Fused fp32 GEMM (dist = 1 - x_hat . k_hat) + per-row top-5 per 128-col block.
// grid = (NCB, B_ROWS/ROW_TILE). block 256 = 16x16, each thread 8x8 outputs
// arranged as 2x2 blocks of 4x4 (rows ty*4+{0..3}/+64, cols tx*4+{0..3}/+64).
// launch_bounds(256,2): cap 256 VGPR — the (256,4) variant squeezed to 64 VGPR
// and spilled the 64-float accumulator to scratch (27 GB of scratch writes).
__global__ __launch_bounds__(256, 2)
void gemm_top5_kernel(const float* __restrict__ x, const float* __restrict__ pk,
                      const float* __restrict__ inv_x, const float* __restrict__ inv_k,
                      float* __restrict__ cand_val, int* __restrict__ cand_idx) {
    const int cb   = blockIdx.x;
    const int rb   = blockIdx.y;
    const int row0 = rb * ROW_TILE;
    const int col0 = cb * COL_TILE;

    __shared__ float As[KB][ROW_TILE + 4];   // k-major; stride 132 floats
    __shared__ float Bs[KB][COL_TILE + 4];

    const int tid = threadIdx.x;
    const int tx = tid & 15, ty = tid >> 4;

    // staging: thread loads rows sr & sr+64, k-cols sk..sk+3 of both panels
    const int sr = tid >> 2;          // 0..63
    const int sk = (tid & 3) * 4;     // 0,4,8,12
    const float iva0 = inv_x[row0 + sr];
    const float iva1 = inv_x[row0 + sr + 64];
    const float ivb0 = inv_k[col0 + sr];
    const float ivb1 = inv_k[col0 + sr + 64];
    const float* ap0 = x  + (size_t)(row0 + sr)      * D_DIM + sk;
    const float* ap1 = x  + (size_t)(row0 + sr + 64) * D_DIM + sk;
    const float* bp0 = pk + (size_t)(col0 + sr)      * D_DIM + sk;
    const float* bp1 = pk + (size_t)(col0 + sr + 64) * D_DIM + sk;

    float acc[8][8] = {};

    for (int k0 = 0; k0 < D_DIM; k0 += KB) {
        float4 a0 = *(const float4*)(ap0 + k0);
        float4 a1 = *(const float4*)(ap1 + k0);
        float4 b0 = *(const float4*)(bp0 + k0);
        float4 b1 = *(const float4*)(bp1 + k0);
        __syncthreads();
        As[sk+0][sr]    = a0.x * iva0; As[sk+1][sr]    = a0.y * iva0;
        As[sk+2][sr]    = a0.z * iva0; As[sk+3][sr]    = a0.w * iva0;
        As[sk+0][sr+64] = a1.x * iva1; As[sk+1][sr+64] = a1.y * iva1;
        As[sk+2][sr+64] = a1.z * iva1; As[sk+3][sr+64] = a1.w * iva1;
        Bs[sk+0][sr]    = b0.x * ivb0; Bs[sk+1][sr]    = b0.y * ivb0;
        Bs[sk+2][sr]    = b0.z * ivb0; Bs[sk+3][sr]    = b0.w * ivb0;
        Bs[sk+0][sr+64] = b1.x * ivb1; Bs[sk+1][sr+64] = b1.y * ivb1;
        Bs[sk+2][sr+64] = b1.z * ivb1; Bs[sk+3][sr+64] = b1.w * ivb1;
        __syncthreads();

        #pragma unroll
        for (int k = 0; k < KB; ++k) {
            float4 al = *(const float4*)&As[k][ty * 4];
            float4 ah = *(const float4*)&As[k][ty * 4 + 64];
            float4 bl = *(const float4*)&Bs[k][tx * 4];
            float4 bh = *(const float4*)&Bs[k][tx * 4 + 64];
            float ar[8] = {al.x, al.y, al.z, al.w, ah.x, ah.y, ah.z, ah.w};
            float br[8] = {bl.x, bl.y, bl.z, bl.w, bh.x, bh.y, bh.z, bh.w};
            #pragma unroll
            for (int i = 0; i < 8; ++i)
                #pragma unroll
                for (int j = 0; j < 8; ++j)
                    acc[i][j] += ar[i] * br[j];
        }
    }

    // epilogue: per row-slot local top5 over 8 cols, then 16-lane butterfly merge
    #pragma unroll
    for (int i = 0; i < 8; ++i) {
        float tv[K_SEL]; int tix[K_SEL];
        #pragma unroll
        for (int j = 0; j < K_SEL; ++j) { tv[j] = 3.0e38f; tix[j] = 0x7fffffff; }
        #pragma unroll
        for (int j = 0; j < 8; ++j) {
            float dv = 1.0f - acc[i][j];
            int c = col0 + tx * 4 + (j >> 2) * 64 + (j & 3);
            insert5(tv, tix, dv, c);
        }
        #pragma unroll
        for (int off = 1; off < 16; off <<= 1) {
            float ov[K_SEL]; int oi[K_SEL];
            #pragma unroll
            for (int j = 0; j < K_SEL; ++j) {
                ov[j] = __shfl_xor(tv[j], off, 16);
                oi[j] = __shfl_xor(tix[j], off, 16);
            }
            #pragma unroll
            for (int j = 0; j < K_SEL; ++j) insert5(tv, tix, ov[j], oi[j]);
        }
        if (tx == 0) {
            int grow = row0 + ty * 4 + (i >> 2) * 64 + (i & 3);
            #pragma unroll
            for (int j = 0; j < K_SEL; ++j) {
                cand_val[((size_t)grow * NCB + cb) * K_SEL + j] = tv[j];
                cand_idx[((size_t)grow * NCB + cb) * K_SEL + j] = tix[j];
            }
        }
    }
}

__global__ __launch_bounds__(256)
void merge_kernel(const float* __restrict__ cand_val, const int* __restrict__ cand_idx,
                  float* __restrict__ out_dist, int* __restrict__ final_idx) {
    int row = blockIdx.x * blockDim.x + threadIdx.x;
    if (row >= B_ROWS) return;
    float fv[K_SEL]; int fi[K_SEL];
    #pragma unroll
    for (int j = 0; j < K_SEL; ++j) { fv[j] = 3.0e38f; fi[j] = 0x7fffffff; }
    for (int t = 0; t < NCB * K_SEL; ++t)
        insert5(fv, fi, cand_val[(size_t)row * NCB * K_SEL + t],
                        cand_idx[(size_t)row * NCB * K_SEL + t]);
    #pragma unroll
    for (int j = 0; j < K_SEL; ++j) {
        out_dist[(size_t)row * K_SEL + j] = fv[j];
        final_idx[(size_t)row * K_SEL + j] = fi[j];
    }
}

// one block per (b, s): copy prompts[idx] (5*768 floats = 960 float4) to output
__global__ __launch_bounds__(256)
void gather_kernel(const float* __restrict__ prompts, const int* __restrict__ final_idx,
                   float* __restrict__ out1) {
    int bs = blockIdx.x;                 // 0 .. B_ROWS*K_SEL-1
    int p = final_idx[bs];
    const float4* src = (const float4*)(prompts + (size_t)p * (L_LEN * D_DIM));
    float4* dst = (float4*)(out1 + (size_t)bs * (L_LEN * D_DIM));
    const int n4 = (L_LEN * D_DIM) / 4;  // 960
    for (int i = threadIdx.x; i < n4; i += blockDim.x) dst[i] = src[i];
}

extern "C" void kernel_launch(void* const* d_in, const int* in_sizes, int n_in,
                              void* d_out, int out_size, void* d_ws, size_t ws_size,
                              hipStream_t stream) {
    const float* x       = (const float*)d_in[0];   // [8192, 768]
    const float* pk      = (const float*)d_in[1];   // [2048, 768]
    const float* prompts = (const float*)d_in[2];   // [2048, 5, 768]

    float* out_dist = (float*)d_out;                          // [8192, 5]
    float* out_pr   = (float*)d_out + (size_t)B_ROWS * K_SEL; // [8192, 5, 5, 768]

    char* ws = (char*)d_ws;
    float* inv_x    = (float*)(ws);                    //    32,768 B
    float* inv_k    = (float*)(ws + 32768);            //     8,192 B
    float* cand_val = (float*)(ws + 40960);            // 2,621,440 B
    int*   cand_idx = (int*)  (ws + 40960 + 2621440);  // 2,621,440 B
    int*   final_ix = (int*)  (ws + 40960 + 5242880);  //   163,840 B

    // 1) inverse norms: (B_ROWS + P_KEYS) waves, 4 waves/block
    norm_kernel<<<(B_ROWS + P_KEYS) / 4, 256, 0, stream>>>(x, pk, inv_x, inv_k);
    // 2) fused GEMM + per-colblock top5
    {
        dim3 grid(NCB, B_ROWS / ROW_TILE);
        gemm_top5_kernel<<<grid, 256, 0, stream>>>(x, pk, inv_x, inv_k, cand_val, cand_idx);
    }
    // 3) cross-colblock merge
    merge_kernel<<<B_ROWS / 256, 256, 0, stream>>>(cand_val, cand_idx, out_dist, final_ix);
    // 4) gather prompts
    gather_kernel<<<B_ROWS * K_SEL, 256, 0, stream>>>(prompts, final_ix, out_pr);
}